// Round 7
// baseline (267.895 us; speedup 1.0000x reference)
//
#include <hip/hip_runtime.h>

// AdjGAT: V=20000, D=256, K=16, O=128, H=4.
// Math: attn[h,v] = x[v].(W_h a_h);  out[v] = relu( (1/H)[ sum_h (sum_k c_hk x[nbr_k]).W_h + sum_h b_h ] )
// Gather x rows (head-independent indices); aggregate y = sum_k c*x, then y.W via MFMA.
// Pipeline (3 launches):
//   KA prep:    blocks 0-63:  W fp32 [h][d][o] -> Wt fp16 in EXACT MFMA B-frag order
//               blocks 64-67: wt[h][d] = sum_o W[h][d][o]*a[h][o]
//   KB xsplit:  xh = fp16(x); attn4[v][h] = x[v].wt[h] (fused)
//   KC gat:     16 nodes/block, 4 waves.
//               P1: softmax coefs (width-16 shuffles).
//               P2: wave w gathers channel slice [w*64,w*64+64) for all 16 nodes
//                   (coalesced 64B/node segments) with double-buffered 4-k load
//                   batches (~16 loads in flight); y fp32 regs in A-frag lane
//                   layout -> fp16 LDS (lane-contiguous, conflict-free).
//               P3: wave w computes cols [w*32,w*32+32) over full K: ds_read_b128
//                   A + dense 1KB global B fragments + 64 MFMAs; no cross-wave
//                   reduction. Epilogue: mean heads + mean bias + relu.
// ws: attn4 0.32MB | xh 10.24MB | Wt 0.26MB | wt 4KB  (~10.8MB)

#define V_N 20000
#define D_N 256
#define K_N 16
#define O_N 128
#define H_N 4
#define NEG_INF -1e9f
#define TM 16            // nodes per block; V = 1250 * 16

typedef _Float16 f16x8 __attribute__((ext_vector_type(8)));
typedef _Float16 f16x4 __attribute__((ext_vector_type(4)));
typedef float    f32x4 __attribute__((ext_vector_type(4)));

// ---------------- KA: prep_w (B-frag swizzle) + wtilde, fused ----------------
__global__ __launch_bounds__(256) void prep_kernel(
    const float* __restrict__ W, const float* __restrict__ a,
    _Float16* __restrict__ Wt, float* __restrict__ wt)
{
    if (blockIdx.x < 64) {
        const int idx  = blockIdx.x * 256 + threadIdx.x;  // 16384 frag-lane slots
        const int lane = idx & 63;
        const int nt   = (idx >> 6) & 7;    // col tile (16 cols)
        const int s    = (idx >> 9) & 7;    // k slice (32 chans)
        const int h    = idx >> 12;
        const int o    = nt * 16 + (lane & 15);
        const int d0   = s * 32 + (lane >> 4) * 8;
        f16x8 v;
        #pragma unroll
        for (int j = 0; j < 8; ++j)
            v[j] = (_Float16)W[((size_t)h * D_N + d0 + j) * O_N + o];
        *(f16x8*)&Wt[(size_t)idx * 8] = v;
    } else {
        const int h = blockIdx.x - 64;
        const int d = threadIdx.x;
        const float* Wrow = W + ((size_t)h * D_N + d) * O_N;
        const float* ah   = a + h * O_N;
        float s = 0.f;
        #pragma unroll
        for (int o = 0; o < O_N; o += 4) {
            const float4 wv = *(const float4*)&Wrow[o];
            const float4 av = *(const float4*)&ah[o];
            s = fmaf(wv.x, av.x, s); s = fmaf(wv.y, av.y, s);
            s = fmaf(wv.z, av.z, s); s = fmaf(wv.w, av.w, s);
        }
        wt[h * D_N + d] = s;
    }
}

// ---------------- KB: x -> fp16 copy + fused attn logits ----------------
__global__ __launch_bounds__(256) void xsplit_attn_kernel(
    const float* __restrict__ x, const float* __restrict__ wt,
    _Float16* __restrict__ xh, float* __restrict__ attn4)
{
    const int wid  = threadIdx.x >> 6;
    const int lane = threadIdx.x & 63;
    const int v    = blockIdx.x * 4 + wid;

    const float4 p = *(const float4*)&x[(size_t)v * D_N + lane * 4];
    f16x4 hv = { (_Float16)p.x, (_Float16)p.y, (_Float16)p.z, (_Float16)p.w };
    *(f16x4*)&xh[(size_t)v * D_N + lane * 4] = hv;

    float s[H_N];
    #pragma unroll
    for (int h = 0; h < H_N; ++h) {
        const float4 w = *(const float4*)&wt[h * D_N + lane * 4];
        float t = fmaf(p.x, w.x, 0.f);
        t = fmaf(p.y, w.y, t); t = fmaf(p.z, w.z, t); t = fmaf(p.w, w.w, t);
        s[h] = t;
    }
    #pragma unroll
    for (int h = 0; h < H_N; ++h)
        #pragma unroll
        for (int dd = 32; dd >= 1; dd >>= 1)
            s[h] += __shfl_xor(s[h], dd);
    if (lane == 0)
        *(float4*)&attn4[(size_t)v * 4] = make_float4(s[0], s[1], s[2], s[3]);
}

// ---------------- KC: fused softmax + pipelined gather + fp16 MFMA ----------
__global__ __launch_bounds__(256, 3) void gat_kernel(
    const _Float16* __restrict__ xh, const float* __restrict__ attn4,
    const _Float16* __restrict__ Wt, const float* __restrict__ b,
    const int* __restrict__ adj, const int* __restrict__ mask_p,
    float* __restrict__ out)
{
    const int v0  = blockIdx.x * TM;
    const int tid = threadIdx.x;

    __shared__ int      sidx_s[TM][17];          // +1 pad
    __shared__ float    coefs_s[K_N][17][H_N];   // [k][node(+pad)][h]
    __shared__ _Float16 yl[H_N * 8 * 64 * 8];    // A-fragment order: 32KB

    // ---- P1: softmax coefs, thread = (node, k) ----
    {
        const int node = tid >> 4;
        const int k    = tid & 15;
        const int mask = mask_p[0];
        const int idx  = adj[(v0 + node) * K_N + k];
        const bool pad = (idx >= mask);
        const int safe = pad ? 0 : idx;
        const float4 av = *(const float4*)&attn4[(size_t)safe * 4];
        const float lg[H_N] = { pad ? NEG_INF : av.x, pad ? NEG_INF : av.y,
                                pad ? NEG_INF : av.z, pad ? NEG_INF : av.w };
        float c[H_N];
        #pragma unroll
        for (int h = 0; h < H_N; ++h) {
            float m = lg[h];
            #pragma unroll
            for (int s = 8; s >= 1; s >>= 1)
                m = fmaxf(m, __shfl_xor(m, s, 16));
            const float e = pad ? 0.f : __expf(lg[h] - m);
            float sum = e;
            #pragma unroll
            for (int s = 8; s >= 1; s >>= 1)
                sum += __shfl_xor(sum, s, 16);
            // pad coef 0 == ref (exp(-1e9-m)==0); all-pad row -> y=0 -> relu(bbar)
            c[h] = pad ? 0.f : e / sum;
        }
        *(float4*)&coefs_s[k][node][0] = make_float4(c[0], c[1], c[2], c[3]);
        sidx_s[node][k] = safe;
    }
    __syncthreads();

    const int wid  = tid >> 6;
    const int lane = tid & 63;
    const int m    = lane & 15;           // node / A-frag row / C col
    const int q    = lane >> 4;           // channel group / C row group

    // ---- P2: pipelined gather-accumulate, channels [wid*64, wid*64+64) ----
    {
        const _Float16* xbase = xh + wid * 64 + q * 8;
        float y0[H_N][8], y1[H_N][8];
        #pragma unroll
        for (int h = 0; h < H_N; ++h)
            #pragma unroll
            for (int j = 0; j < 8; ++j) { y0[h][j] = 0.f; y1[h][j] = 0.f; }

        f16x8 la[2][4], lb[2][4];
        #pragma unroll
        for (int kk = 0; kk < 4; ++kk) {       // prefetch batch 0
            const int si = sidx_s[m][kk];
            la[0][kk] = *(const f16x8*)&xbase[(size_t)si * D_N];
            lb[0][kk] = *(const f16x8*)&xbase[(size_t)si * D_N + 32];
        }
        #pragma unroll
        for (int kb = 0; kb < 4; ++kb) {
            const int cur = kb & 1, nxt = cur ^ 1;
            if (kb < 3) {                      // prefetch next batch
                #pragma unroll
                for (int kk = 0; kk < 4; ++kk) {
                    const int k  = (kb + 1) * 4 + kk;
                    const int si = sidx_s[m][k];
                    la[nxt][kk] = *(const f16x8*)&xbase[(size_t)si * D_N];
                    lb[nxt][kk] = *(const f16x8*)&xbase[(size_t)si * D_N + 32];
                }
            }
            #pragma unroll
            for (int kk = 0; kk < 4; ++kk) {   // consume current batch
                const int k = kb * 4 + kk;
                const float4 c = *(const float4*)&coefs_s[k][m][0];
                const float ch[H_N] = { c.x, c.y, c.z, c.w };
                #pragma unroll
                for (int h = 0; h < H_N; ++h)
                    #pragma unroll
                    for (int j = 0; j < 8; ++j) {
                        y0[h][j] = fmaf(ch[h], (float)la[cur][kk][j], y0[h][j]);
                        y1[h][j] = fmaf(ch[h], (float)lb[cur][kk][j], y1[h][j]);
                    }
            }
        }
        // write y as fp16 A-fragments: slices wid*2, wid*2+1; lane-contiguous.
        #pragma unroll
        for (int h = 0; h < H_N; ++h) {
            f16x8 v0, v1;
            #pragma unroll
            for (int j = 0; j < 8; ++j) {
                v0[j] = (_Float16)y0[h][j];
                v1[j] = (_Float16)y1[h][j];
            }
            *(f16x8*)&yl[(((h * 8 + wid * 2 + 0) * 64) + lane) * 8] = v0;
            *(f16x8*)&yl[(((h * 8 + wid * 2 + 1) * 64) + lane) * 8] = v1;
        }
    }
    __syncthreads();

    // ---- P3: cols [wid*32, wid*32+32) over full K (4h x 8 slices) ----
    f32x4 acc0 = (f32x4){0.f, 0.f, 0.f, 0.f};
    f32x4 acc1 = (f32x4){0.f, 0.f, 0.f, 0.f};
    {
        const _Float16* Wb = Wt + (size_t)lane * 8;
        #pragma unroll
        for (int h = 0; h < H_N; ++h) {
            #pragma unroll
            for (int s = 0; s < 8; ++s) {
                const f16x8 af = *(const f16x8*)&yl[((h * 8 + s) * 64 + lane) * 8];
                const size_t fb = (size_t)((h * 8 + s) * 8 + wid * 2) * 512;
                const f16x8 b0 = *(const f16x8*)&Wb[fb];
                const f16x8 b1 = *(const f16x8*)&Wb[fb + 512];
                acc0 = __builtin_amdgcn_mfma_f32_16x16x32_f16(af, b0, acc0, 0, 0, 0);
                acc1 = __builtin_amdgcn_mfma_f32_16x16x32_f16(af, b1, acc1, 0, 0, 0);
            }
        }
    }

    // ---- epilogue: mean heads + mean bias + relu; C: col=m, row=q*4+r ----
    #pragma unroll
    for (int nt = 0; nt < 2; ++nt) {
        const f32x4 acc = nt ? acc1 : acc0;
        const int col = (wid * 2 + nt) * 16 + m;
        const float bb = b[col] + b[O_N + col] + b[2 * O_N + col] + b[3 * O_N + col];
        #pragma unroll
        for (int r = 0; r < 4; ++r) {
            const int node = q * 4 + r;
            out[(size_t)(v0 + node) * O_N + col] = fmaxf(0.25f * (acc[r] + bb), 0.f);
        }
    }
}

extern "C" void kernel_launch(void* const* d_in, const int* in_sizes, int n_in,
                              void* d_out, int out_size, void* d_ws, size_t ws_size,
                              hipStream_t stream) {
    const float* x      = (const float*)d_in[0];
    const float* W      = (const float*)d_in[1];
    const float* a      = (const float*)d_in[2];
    const float* b      = (const float*)d_in[3];
    const int*   adj    = (const int*)d_in[4];
    const int*   mask_p = (const int*)d_in[5];
    float*       out    = (float*)d_out;

    // ws layout (bytes)
    char* p = (char*)d_ws;
    float*    attn4 = (float*)p;                     //    320,000
    _Float16* xh    = (_Float16*)(p + 320000);       // 10,240,000
    _Float16* Wt    = (_Float16*)(p + 10560000);     //    262,144
    float*    wt    = (float*)(p + 10822144);        //      4,096  (~10.8MB)

    prep_kernel<<<68, 256, 0, stream>>>(W, a, Wt, wt);
    xsplit_attn_kernel<<<V_N / 4, 256, 0, stream>>>(x, wt, xh, attn4);
    gat_kernel<<<V_N / TM, 256, 0, stream>>>(xh, attn4, Wt, b, adj, mask_p, out);
}

// Round 8
// 217.353 us; speedup vs baseline: 1.2325x; 1.2325x over previous
//
#include <hip/hip_runtime.h>

// AdjGAT: V=20000, D=256, K=16, O=128, H=4.
// Math: attn[h,v] = x[v].(W_h a_h);  out[v] = relu( (1/H)[ sum_h (sum_k c_hk x[nbr_k]).W_h + sum_h b_h ] )
// Gather x rows (head-independent indices); aggregate y = sum_k c*x, then y.W via MFMA.
// Pipeline (3 launches):
//   KA prep:    blocks 0-63:  W fp32 [h][d][o] -> Wt fp16 in EXACT MFMA B-frag order
//               blocks 64-67: wt[h][d] = sum_o W[h][d][o]*a[h][o]
//   KB xsplit:  xh = fp16(x); attn4[v][h] = x[v].wt[h] (fused)
//   KC gat:     16 nodes/block, 4 waves.
//               P1: softmax coefs (width-16 shuffles).
//               P2: wave w gathers channel slice [w*64,w*64+64) for all 16 nodes
//                   (coalesced 64B/node segments); k-loop FULLY unrolled with
//                   preloaded indices -> compiler hoists many independent loads
//                   (no dynamically-indexed local arrays -> no scratch; R7 bug).
//               P3: wave w computes cols [w*32,w*32+32) over full K: ds_read_b128
//                   A + dense 1KB global B fragments + 64 MFMAs; no cross-wave
//                   reduction. Epilogue: mean heads + mean bias + relu.
// ws: attn4 0.32MB | xh 10.24MB | Wt 0.26MB | wt 4KB  (~10.8MB)

#define V_N 20000
#define D_N 256
#define K_N 16
#define O_N 128
#define H_N 4
#define NEG_INF -1e9f
#define TM 16            // nodes per block; V = 1250 * 16

typedef _Float16 f16x8 __attribute__((ext_vector_type(8)));
typedef _Float16 f16x4 __attribute__((ext_vector_type(4)));
typedef float    f32x4 __attribute__((ext_vector_type(4)));

// ---------------- KA: prep_w (B-frag swizzle) + wtilde, fused ----------------
__global__ __launch_bounds__(256) void prep_kernel(
    const float* __restrict__ W, const float* __restrict__ a,
    _Float16* __restrict__ Wt, float* __restrict__ wt)
{
    if (blockIdx.x < 64) {
        const int idx  = blockIdx.x * 256 + threadIdx.x;  // 16384 frag-lane slots
        const int lane = idx & 63;
        const int nt   = (idx >> 6) & 7;    // col tile (16 cols)
        const int s    = (idx >> 9) & 7;    // k slice (32 chans)
        const int h    = idx >> 12;
        const int o    = nt * 16 + (lane & 15);
        const int d0   = s * 32 + (lane >> 4) * 8;
        f16x8 v;
        #pragma unroll
        for (int j = 0; j < 8; ++j)
            v[j] = (_Float16)W[((size_t)h * D_N + d0 + j) * O_N + o];
        *(f16x8*)&Wt[(size_t)idx * 8] = v;
    } else {
        const int h = blockIdx.x - 64;
        const int d = threadIdx.x;
        const float* Wrow = W + ((size_t)h * D_N + d) * O_N;
        const float* ah   = a + h * O_N;
        float s = 0.f;
        #pragma unroll
        for (int o = 0; o < O_N; o += 4) {
            const float4 wv = *(const float4*)&Wrow[o];
            const float4 av = *(const float4*)&ah[o];
            s = fmaf(wv.x, av.x, s); s = fmaf(wv.y, av.y, s);
            s = fmaf(wv.z, av.z, s); s = fmaf(wv.w, av.w, s);
        }
        wt[h * D_N + d] = s;
    }
}

// ---------------- KB: x -> fp16 copy + fused attn logits ----------------
__global__ __launch_bounds__(256) void xsplit_attn_kernel(
    const float* __restrict__ x, const float* __restrict__ wt,
    _Float16* __restrict__ xh, float* __restrict__ attn4)
{
    const int wid  = threadIdx.x >> 6;
    const int lane = threadIdx.x & 63;
    const int v    = blockIdx.x * 4 + wid;

    const float4 p = *(const float4*)&x[(size_t)v * D_N + lane * 4];
    f16x4 hv = { (_Float16)p.x, (_Float16)p.y, (_Float16)p.z, (_Float16)p.w };
    *(f16x4*)&xh[(size_t)v * D_N + lane * 4] = hv;

    float s[H_N];
    #pragma unroll
    for (int h = 0; h < H_N; ++h) {
        const float4 w = *(const float4*)&wt[h * D_N + lane * 4];
        float t = fmaf(p.x, w.x, 0.f);
        t = fmaf(p.y, w.y, t); t = fmaf(p.z, w.z, t); t = fmaf(p.w, w.w, t);
        s[h] = t;
    }
    #pragma unroll
    for (int h = 0; h < H_N; ++h)
        #pragma unroll
        for (int dd = 32; dd >= 1; dd >>= 1)
            s[h] += __shfl_xor(s[h], dd);
    if (lane == 0)
        *(float4*)&attn4[(size_t)v * 4] = make_float4(s[0], s[1], s[2], s[3]);
}

// ---------------- KC: fused softmax + gather + full-K fp16 MFMA -------------
__global__ __launch_bounds__(256, 3) void gat_kernel(
    const _Float16* __restrict__ xh, const float* __restrict__ attn4,
    const _Float16* __restrict__ Wt, const float* __restrict__ b,
    const int* __restrict__ adj, const int* __restrict__ mask_p,
    float* __restrict__ out)
{
    const int v0  = blockIdx.x * TM;
    const int tid = threadIdx.x;

    __shared__ int      sidx_s[TM][17];          // +1 pad
    __shared__ float    coefs_s[K_N][17][H_N];   // [k][node(+pad)][h]
    __shared__ _Float16 yl[H_N * 8 * 64 * 8];    // A-fragment order: 32KB

    // ---- P1: softmax coefs, thread = (node, k) ----
    {
        const int node = tid >> 4;
        const int k    = tid & 15;
        const int mask = mask_p[0];
        const int idx  = adj[(v0 + node) * K_N + k];
        const bool pad = (idx >= mask);
        const int safe = pad ? 0 : idx;
        const float4 av = *(const float4*)&attn4[(size_t)safe * 4];
        const float lg[H_N] = { pad ? NEG_INF : av.x, pad ? NEG_INF : av.y,
                                pad ? NEG_INF : av.z, pad ? NEG_INF : av.w };
        float c[H_N];
        #pragma unroll
        for (int h = 0; h < H_N; ++h) {
            float m = lg[h];
            #pragma unroll
            for (int s = 8; s >= 1; s >>= 1)
                m = fmaxf(m, __shfl_xor(m, s, 16));
            const float e = pad ? 0.f : __expf(lg[h] - m);
            float sum = e;
            #pragma unroll
            for (int s = 8; s >= 1; s >>= 1)
                sum += __shfl_xor(sum, s, 16);
            // pad coef 0 == ref (exp(-1e9-m)==0); all-pad row -> y=0 -> relu(bbar)
            c[h] = pad ? 0.f : e / sum;
        }
        *(float4*)&coefs_s[k][node][0] = make_float4(c[0], c[1], c[2], c[3]);
        sidx_s[node][k] = safe;
    }
    __syncthreads();

    const int wid  = tid >> 6;
    const int lane = tid & 63;
    const int m    = lane & 15;           // node / A-frag row / C col
    const int q    = lane >> 4;           // channel group / C row group

    // ---- P2: gather-accumulate channel slice [wid*64, wid*64+64) ----
    {
        const _Float16* xbase = xh + wid * 64 + q * 8;

        // preload gather indices (constant LDS offsets; address chains for the
        // global loads then have no pending-LDS dependency)
        int si[K_N];
        #pragma unroll
        for (int k = 0; k < K_N; ++k) si[k] = sidx_s[m][k];

        float y0[H_N][8], y1[H_N][8];
        #pragma unroll
        for (int h = 0; h < H_N; ++h)
            #pragma unroll
            for (int j = 0; j < 8; ++j) { y0[h][j] = 0.f; y1[h][j] = 0.f; }

        #pragma unroll
        for (int k = 0; k < K_N; ++k) {   // FULL unroll: constant indices, no scratch
            const f16x8 xa = *(const f16x8*)&xbase[(size_t)si[k] * D_N];
            const f16x8 xb = *(const f16x8*)&xbase[(size_t)si[k] * D_N + 32];
            const float4 c = *(const float4*)&coefs_s[k][m][0];
            const float ch[H_N] = { c.x, c.y, c.z, c.w };
            #pragma unroll
            for (int h = 0; h < H_N; ++h)
                #pragma unroll
                for (int j = 0; j < 8; ++j) {
                    y0[h][j] = fmaf(ch[h], (float)xa[j], y0[h][j]);
                    y1[h][j] = fmaf(ch[h], (float)xb[j], y1[h][j]);
                }
        }
        // write y as fp16 A-fragments: slices wid*2, wid*2+1; lane-contiguous.
        #pragma unroll
        for (int h = 0; h < H_N; ++h) {
            f16x8 v0, v1;
            #pragma unroll
            for (int j = 0; j < 8; ++j) {
                v0[j] = (_Float16)y0[h][j];
                v1[j] = (_Float16)y1[h][j];
            }
            *(f16x8*)&yl[(((h * 8 + wid * 2 + 0) * 64) + lane) * 8] = v0;
            *(f16x8*)&yl[(((h * 8 + wid * 2 + 1) * 64) + lane) * 8] = v1;
        }
    }
    __syncthreads();

    // ---- P3: cols [wid*32, wid*32+32) over full K (4h x 8 slices) ----
    f32x4 acc0 = (f32x4){0.f, 0.f, 0.f, 0.f};
    f32x4 acc1 = (f32x4){0.f, 0.f, 0.f, 0.f};
    {
        const _Float16* Wb = Wt + (size_t)lane * 8;
        #pragma unroll
        for (int h = 0; h < H_N; ++h) {
            #pragma unroll
            for (int s = 0; s < 8; ++s) {
                const f16x8 af = *(const f16x8*)&yl[((h * 8 + s) * 64 + lane) * 8];
                const size_t fb = (size_t)((h * 8 + s) * 8 + wid * 2) * 512;
                const f16x8 b0 = *(const f16x8*)&Wb[fb];
                const f16x8 b1 = *(const f16x8*)&Wb[fb + 512];
                acc0 = __builtin_amdgcn_mfma_f32_16x16x32_f16(af, b0, acc0, 0, 0, 0);
                acc1 = __builtin_amdgcn_mfma_f32_16x16x32_f16(af, b1, acc1, 0, 0, 0);
            }
        }
    }

    // ---- epilogue: mean heads + mean bias + relu; C: col=m, row=q*4+r ----
    #pragma unroll
    for (int nt = 0; nt < 2; ++nt) {
        const f32x4 acc = nt ? acc1 : acc0;
        const int col = (wid * 2 + nt) * 16 + m;
        const float bb = b[col] + b[O_N + col] + b[2 * O_N + col] + b[3 * O_N + col];
        #pragma unroll
        for (int r = 0; r < 4; ++r) {
            const int node = q * 4 + r;
            out[(size_t)(v0 + node) * O_N + col] = fmaxf(0.25f * (acc[r] + bb), 0.f);
        }
    }
}

extern "C" void kernel_launch(void* const* d_in, const int* in_sizes, int n_in,
                              void* d_out, int out_size, void* d_ws, size_t ws_size,
                              hipStream_t stream) {
    const float* x      = (const float*)d_in[0];
    const float* W      = (const float*)d_in[1];
    const float* a      = (const float*)d_in[2];
    const float* b      = (const float*)d_in[3];
    const int*   adj    = (const int*)d_in[4];
    const int*   mask_p = (const int*)d_in[5];
    float*       out    = (float*)d_out;

    // ws layout (bytes)
    char* p = (char*)d_ws;
    float*    attn4 = (float*)p;                     //    320,000
    _Float16* xh    = (_Float16*)(p + 320000);       // 10,240,000
    _Float16* Wt    = (_Float16*)(p + 10560000);     //    262,144
    float*    wt    = (float*)(p + 10822144);        //      4,096  (~10.8MB)

    prep_kernel<<<68, 256, 0, stream>>>(W, a, Wt, wt);
    xsplit_attn_kernel<<<V_N / 4, 256, 0, stream>>>(x, wt, xh, attn4);
    gat_kernel<<<V_N / TM, 256, 0, stream>>>(xh, attn4, Wt, b, adj, mask_p, out);
}

// Round 9
// 160.357 us; speedup vs baseline: 1.6706x; 1.3554x over previous
//
#include <hip/hip_runtime.h>

// AdjGAT: V=20000, D=256, K=16, O=128, H=4.
// Math: attn[h,v] = x[v].(W_h a_h);  out[v] = relu( (1/H)[ sum_h (sum_k c_hk x[nbr_k]).W_h + sum_h b_h ] )
// Gather x rows (head-independent indices); aggregate y = sum_k c*x, then y.W via MFMA.
// Pipeline (3 launches):
//   KA prep:    blocks 0-63:  W fp32 [h][d][o] -> Wt fp16 in EXACT MFMA B-frag order
//               blocks 64-67: wt[h][d] = sum_o W[h][d][o]*a[h][o]
//   KB xsplit:  xh = fp16(x); attn4[v][h] = x[v].wt[h] (fused)
//   KC gat:     16 nodes/block, 512 thr = 8 waves (halved per-wave reg pressure
//               vs R6; R7/R8 lesson: keep live set << VGPR cap or loads spill).
//               P1: softmax coefs (width-16 shuffles, first 256 threads).
//               P2: wave w gathers channel slice [w*32,w*32+32) for all 16 nodes
//                   (coalesced 64B/node segments), two 8-load batches in flight;
//                   y (32 fp32) in A-frag lane layout -> fp16 LDS slice s=w.
//               P3: wave w computes col tile [w*16,w*16+16) over full K:
//                   32 ds_read_b128 A + 32 dense 1KB global B frags + 32 MFMAs.
//               Epilogue: mean heads + mean bias + relu.
// ws: attn4 0.32MB | xh 10.24MB | Wt 0.26MB | wt 4KB  (~10.8MB)

#define V_N 20000
#define D_N 256
#define K_N 16
#define O_N 128
#define H_N 4
#define NEG_INF -1e9f
#define TM 16            // nodes per block; V = 1250 * 16

typedef _Float16 f16x8 __attribute__((ext_vector_type(8)));
typedef _Float16 f16x4 __attribute__((ext_vector_type(4)));
typedef float    f32x4 __attribute__((ext_vector_type(4)));

// ---------------- KA: prep_w (B-frag swizzle) + wtilde, fused ----------------
__global__ __launch_bounds__(256) void prep_kernel(
    const float* __restrict__ W, const float* __restrict__ a,
    _Float16* __restrict__ Wt, float* __restrict__ wt)
{
    if (blockIdx.x < 64) {
        const int idx  = blockIdx.x * 256 + threadIdx.x;  // 16384 frag-lane slots
        const int lane = idx & 63;
        const int nt   = (idx >> 6) & 7;    // col tile (16 cols)
        const int s    = (idx >> 9) & 7;    // k slice (32 chans)
        const int h    = idx >> 12;
        const int o    = nt * 16 + (lane & 15);
        const int d0   = s * 32 + (lane >> 4) * 8;
        f16x8 v;
        #pragma unroll
        for (int j = 0; j < 8; ++j)
            v[j] = (_Float16)W[((size_t)h * D_N + d0 + j) * O_N + o];
        *(f16x8*)&Wt[(size_t)idx * 8] = v;
    } else {
        const int h = blockIdx.x - 64;
        const int d = threadIdx.x;
        const float* Wrow = W + ((size_t)h * D_N + d) * O_N;
        const float* ah   = a + h * O_N;
        float s = 0.f;
        #pragma unroll
        for (int o = 0; o < O_N; o += 4) {
            const float4 wv = *(const float4*)&Wrow[o];
            const float4 av = *(const float4*)&ah[o];
            s = fmaf(wv.x, av.x, s); s = fmaf(wv.y, av.y, s);
            s = fmaf(wv.z, av.z, s); s = fmaf(wv.w, av.w, s);
        }
        wt[h * D_N + d] = s;
    }
}

// ---------------- KB: x -> fp16 copy + fused attn logits ----------------
__global__ __launch_bounds__(256) void xsplit_attn_kernel(
    const float* __restrict__ x, const float* __restrict__ wt,
    _Float16* __restrict__ xh, float* __restrict__ attn4)
{
    const int wid  = threadIdx.x >> 6;
    const int lane = threadIdx.x & 63;
    const int v    = blockIdx.x * 4 + wid;

    const float4 p = *(const float4*)&x[(size_t)v * D_N + lane * 4];
    f16x4 hv = { (_Float16)p.x, (_Float16)p.y, (_Float16)p.z, (_Float16)p.w };
    *(f16x4*)&xh[(size_t)v * D_N + lane * 4] = hv;

    float s[H_N];
    #pragma unroll
    for (int h = 0; h < H_N; ++h) {
        const float4 w = *(const float4*)&wt[h * D_N + lane * 4];
        float t = fmaf(p.x, w.x, 0.f);
        t = fmaf(p.y, w.y, t); t = fmaf(p.z, w.z, t); t = fmaf(p.w, w.w, t);
        s[h] = t;
    }
    #pragma unroll
    for (int h = 0; h < H_N; ++h)
        #pragma unroll
        for (int dd = 32; dd >= 1; dd >>= 1)
            s[h] += __shfl_xor(s[h], dd);
    if (lane == 0)
        *(float4*)&attn4[(size_t)v * 4] = make_float4(s[0], s[1], s[2], s[3]);
}

// ---------------- KC: fused softmax + gather + full-K fp16 MFMA -------------
__global__ __launch_bounds__(512, 4) void gat_kernel(
    const _Float16* __restrict__ xh, const float* __restrict__ attn4,
    const _Float16* __restrict__ Wt, const float* __restrict__ b,
    const int* __restrict__ adj, const int* __restrict__ mask_p,
    float* __restrict__ out)
{
    const int v0  = blockIdx.x * TM;
    const int tid = threadIdx.x;

    __shared__ int      sidx_s[TM][17];          // +1 pad
    __shared__ float    coefs_s[K_N][17][H_N];   // [k][node(+pad)][h]
    __shared__ _Float16 yl[H_N * 8 * 64 * 8];    // A-fragment order: 32KB

    // ---- P1: softmax coefs, thread = (node, k), first 256 threads ----
    if (tid < 256) {
        const int node = tid >> 4;
        const int k    = tid & 15;
        const int mask = mask_p[0];
        const int idx  = adj[(v0 + node) * K_N + k];
        const bool pad = (idx >= mask);
        const int safe = pad ? 0 : idx;
        const float4 av = *(const float4*)&attn4[(size_t)safe * 4];
        const float lg[H_N] = { pad ? NEG_INF : av.x, pad ? NEG_INF : av.y,
                                pad ? NEG_INF : av.z, pad ? NEG_INF : av.w };
        float c[H_N];
        #pragma unroll
        for (int h = 0; h < H_N; ++h) {
            float m = lg[h];
            #pragma unroll
            for (int s = 8; s >= 1; s >>= 1)
                m = fmaxf(m, __shfl_xor(m, s, 16));
            const float e = pad ? 0.f : __expf(lg[h] - m);
            float sum = e;
            #pragma unroll
            for (int s = 8; s >= 1; s >>= 1)
                sum += __shfl_xor(sum, s, 16);
            // pad coef 0 == ref (exp(-1e9-m)==0); all-pad row -> y=0 -> relu(bbar)
            c[h] = pad ? 0.f : e / sum;
        }
        *(float4*)&coefs_s[k][node][0] = make_float4(c[0], c[1], c[2], c[3]);
        sidx_s[node][k] = safe;
    }
    __syncthreads();

    const int wid  = tid >> 6;            // 0..7: k-slice (P2) / col tile (P3)
    const int lane = tid & 63;
    const int m    = lane & 15;           // node / A-frag row / C col
    const int q    = lane >> 4;           // channel group / C row group

    // ---- P2: gather-accumulate channel slice [wid*32, wid*32+32) ----
    {
        const _Float16* xbase = xh + wid * 32 + q * 8;

        float y[H_N][8];
        #pragma unroll
        for (int h = 0; h < H_N; ++h)
            #pragma unroll
            for (int j = 0; j < 8; ++j) y[h][j] = 0.f;

        f16x8 xv[8];
        // batch 0: k = 0..7 (8 x 16B loads in flight, 32 VGPRs)
        #pragma unroll
        for (int kk = 0; kk < 8; ++kk)
            xv[kk] = *(const f16x8*)&xbase[(size_t)sidx_s[m][kk] * D_N];
        #pragma unroll
        for (int kk = 0; kk < 8; ++kk) {
            const float4 c = *(const float4*)&coefs_s[kk][m][0];
            const float ch[H_N] = { c.x, c.y, c.z, c.w };
            #pragma unroll
            for (int h = 0; h < H_N; ++h)
                #pragma unroll
                for (int j = 0; j < 8; ++j)
                    y[h][j] = fmaf(ch[h], (float)xv[kk][j], y[h][j]);
        }
        // batch 1: k = 8..15
        #pragma unroll
        for (int kk = 0; kk < 8; ++kk)
            xv[kk] = *(const f16x8*)&xbase[(size_t)sidx_s[m][kk + 8] * D_N];
        #pragma unroll
        for (int kk = 0; kk < 8; ++kk) {
            const float4 c = *(const float4*)&coefs_s[kk + 8][m][0];
            const float ch[H_N] = { c.x, c.y, c.z, c.w };
            #pragma unroll
            for (int h = 0; h < H_N; ++h)
                #pragma unroll
                for (int j = 0; j < 8; ++j)
                    y[h][j] = fmaf(ch[h], (float)xv[kk][j], y[h][j]);
        }
        // write y as fp16 A-fragments: slice s = wid; lane-contiguous.
        #pragma unroll
        for (int h = 0; h < H_N; ++h) {
            f16x8 v;
            #pragma unroll
            for (int j = 0; j < 8; ++j) v[j] = (_Float16)y[h][j];
            *(f16x8*)&yl[((h * 8 + wid) * 64 + lane) * 8] = v;
        }
    }
    __syncthreads();

    // ---- P3: col tile [wid*16, wid*16+16) over full K (4h x 8 slices) ----
    f32x4 acc = (f32x4){0.f, 0.f, 0.f, 0.f};
    {
        const _Float16* Wb = Wt + (size_t)lane * 8;
        #pragma unroll
        for (int h = 0; h < H_N; ++h) {
            #pragma unroll
            for (int s = 0; s < 8; ++s) {
                const f16x8 af = *(const f16x8*)&yl[((h * 8 + s) * 64 + lane) * 8];
                const f16x8 bf = *(const f16x8*)&Wb[(size_t)((h * 8 + s) * 8 + wid) * 512];
                acc = __builtin_amdgcn_mfma_f32_16x16x32_f16(af, bf, acc, 0, 0, 0);
            }
        }
    }

    // ---- epilogue: mean heads + mean bias + relu; C: col=m, row=q*4+r ----
    {
        const int col = wid * 16 + m;
        const float bb = b[col] + b[O_N + col] + b[2 * O_N + col] + b[3 * O_N + col];
        #pragma unroll
        for (int r = 0; r < 4; ++r) {
            const int node = q * 4 + r;
            out[(size_t)(v0 + node) * O_N + col] = fmaxf(0.25f * (acc[r] + bb), 0.f);
        }
    }
}

extern "C" void kernel_launch(void* const* d_in, const int* in_sizes, int n_in,
                              void* d_out, int out_size, void* d_ws, size_t ws_size,
                              hipStream_t stream) {
    const float* x      = (const float*)d_in[0];
    const float* W      = (const float*)d_in[1];
    const float* a      = (const float*)d_in[2];
    const float* b      = (const float*)d_in[3];
    const int*   adj    = (const int*)d_in[4];
    const int*   mask_p = (const int*)d_in[5];
    float*       out    = (float*)d_out;

    // ws layout (bytes)
    char* p = (char*)d_ws;
    float*    attn4 = (float*)p;                     //    320,000
    _Float16* xh    = (_Float16*)(p + 320000);       // 10,240,000
    _Float16* Wt    = (_Float16*)(p + 10560000);     //    262,144
    float*    wt    = (float*)(p + 10822144);        //      4,096  (~10.8MB)

    prep_kernel<<<68, 256, 0, stream>>>(W, a, Wt, wt);
    xsplit_attn_kernel<<<V_N / 4, 256, 0, stream>>>(x, wt, xh, attn4);
    gat_kernel<<<V_N / TM, 512, 0, stream>>>(xh, attn4, Wt, b, adj, mask_p, out);
}

// Round 10
// 128.075 us; speedup vs baseline: 2.0917x; 1.2521x over previous
//
#include <hip/hip_runtime.h>

// AdjGAT: V=20000, D=256, K=16, O=128, H=4.
// Math: attn[h,v] = x[v].(W_h a_h);  out[v] = relu( (1/H)[ sum_h (sum_k c_hk x[nbr_k]).W_h + sum_h b_h ] )
// Gather x rows (head-independent indices); aggregate y = sum_k c*x, then y.W via MFMA.
// Pipeline (3 launches):
//   KA prep:    blocks 0-63:  W fp32 [h][d][o] -> Wt fp16 in EXACT MFMA B-frag order
//               blocks 64-67: wt[h][d] = sum_o W[h][d][o]*a[h][o]
//   KB xsplit:  xh = fp16(x); attn4[v][h] = x[v].wt[h] (fused)
//   KC gat:     16 nodes/block, 256 thr = 4 waves (R6 register structure: the only
//               proven no-spill shape; R7-R9 lesson: bigger load batches => scratch).
//               P1: softmax coefs (width-16 shuffles).
//               P2: wave owns nodes [wid*4,wid*4+4) x FULL 256-ch rows; each load
//                   instr = 2 contiguous 512B rows (2 segments, was 16 scattered
//                   64B segments in R6) -> far fewer TA/L2 requests, same bytes,
//                   same reg pressure. y (2x4x8 fp32) -> fp16 LDS in A-frag order
//                   with XOR swizzle (sl^n): write contiguous, read <=2-way.
//               P3: wave computes col tiles wid*2, wid*2+1 over full K:
//                   ds_read_b128 A + dense 1KB global B frags + 64 MFMAs.
//               Epilogue: mean heads + mean bias + relu.
// ws: attn4 0.32MB | xh 10.24MB | Wt 0.26MB | wt 4KB  (~10.8MB)

#define V_N 20000
#define D_N 256
#define K_N 16
#define O_N 128
#define H_N 4
#define NEG_INF -1e9f
#define TM 16            // nodes per block; V = 1250 * 16

typedef _Float16 f16x8 __attribute__((ext_vector_type(8)));
typedef _Float16 f16x4 __attribute__((ext_vector_type(4)));
typedef float    f32x4 __attribute__((ext_vector_type(4)));

// ---------------- KA: prep_w (B-frag swizzle) + wtilde, fused ----------------
__global__ __launch_bounds__(256) void prep_kernel(
    const float* __restrict__ W, const float* __restrict__ a,
    _Float16* __restrict__ Wt, float* __restrict__ wt)
{
    if (blockIdx.x < 64) {
        const int idx  = blockIdx.x * 256 + threadIdx.x;  // 16384 frag-lane slots
        const int lane = idx & 63;
        const int nt   = (idx >> 6) & 7;    // col tile (16 cols)
        const int s    = (idx >> 9) & 7;    // k slice (32 chans)
        const int h    = idx >> 12;
        const int o    = nt * 16 + (lane & 15);
        const int d0   = s * 32 + (lane >> 4) * 8;
        f16x8 v;
        #pragma unroll
        for (int j = 0; j < 8; ++j)
            v[j] = (_Float16)W[((size_t)h * D_N + d0 + j) * O_N + o];
        *(f16x8*)&Wt[(size_t)idx * 8] = v;
    } else {
        const int h = blockIdx.x - 64;
        const int d = threadIdx.x;
        const float* Wrow = W + ((size_t)h * D_N + d) * O_N;
        const float* ah   = a + h * O_N;
        float s = 0.f;
        #pragma unroll
        for (int o = 0; o < O_N; o += 4) {
            const float4 wv = *(const float4*)&Wrow[o];
            const float4 av = *(const float4*)&ah[o];
            s = fmaf(wv.x, av.x, s); s = fmaf(wv.y, av.y, s);
            s = fmaf(wv.z, av.z, s); s = fmaf(wv.w, av.w, s);
        }
        wt[h * D_N + d] = s;
    }
}

// ---------------- KB: x -> fp16 copy + fused attn logits ----------------
__global__ __launch_bounds__(256) void xsplit_attn_kernel(
    const float* __restrict__ x, const float* __restrict__ wt,
    _Float16* __restrict__ xh, float* __restrict__ attn4)
{
    const int wid  = threadIdx.x >> 6;
    const int lane = threadIdx.x & 63;
    const int v    = blockIdx.x * 4 + wid;

    const float4 p = *(const float4*)&x[(size_t)v * D_N + lane * 4];
    f16x4 hv = { (_Float16)p.x, (_Float16)p.y, (_Float16)p.z, (_Float16)p.w };
    *(f16x4*)&xh[(size_t)v * D_N + lane * 4] = hv;

    float s[H_N];
    #pragma unroll
    for (int h = 0; h < H_N; ++h) {
        const float4 w = *(const float4*)&wt[h * D_N + lane * 4];
        float t = fmaf(p.x, w.x, 0.f);
        t = fmaf(p.y, w.y, t); t = fmaf(p.z, w.z, t); t = fmaf(p.w, w.w, t);
        s[h] = t;
    }
    #pragma unroll
    for (int h = 0; h < H_N; ++h)
        #pragma unroll
        for (int dd = 32; dd >= 1; dd >>= 1)
            s[h] += __shfl_xor(s[h], dd);
    if (lane == 0)
        *(float4*)&attn4[(size_t)v * 4] = make_float4(s[0], s[1], s[2], s[3]);
}

// ---------------- KC: fused softmax + row-gather + full-K fp16 MFMA ---------
__global__ __launch_bounds__(256, 4) void gat_kernel(
    const _Float16* __restrict__ xh, const float* __restrict__ attn4,
    const _Float16* __restrict__ Wt, const float* __restrict__ b,
    const int* __restrict__ adj, const int* __restrict__ mask_p,
    float* __restrict__ out)
{
    const int v0  = blockIdx.x * TM;
    const int tid = threadIdx.x;

    __shared__ int      sidx_s[TM][17];          // +1 pad
    __shared__ float    coefs_s[K_N][17][H_N];   // [k][node(+pad)][h]
    // yl slot (f16x8 units): h*512 + n*32 + (sl ^ n); sl = s*4 + q' (32B slot of row)
    __shared__ _Float16 yl[H_N * 512 * 8];       // 32KB

    // ---- P1: softmax coefs, thread = (node, k) ----
    {
        const int node = tid >> 4;
        const int k    = tid & 15;
        const int mask = mask_p[0];
        const int idx  = adj[(v0 + node) * K_N + k];
        const bool pad = (idx >= mask);
        const int safe = pad ? 0 : idx;
        const float4 av = *(const float4*)&attn4[(size_t)safe * 4];
        const float lg[H_N] = { pad ? NEG_INF : av.x, pad ? NEG_INF : av.y,
                                pad ? NEG_INF : av.z, pad ? NEG_INF : av.w };
        float c[H_N];
        #pragma unroll
        for (int h = 0; h < H_N; ++h) {
            float m = lg[h];
            #pragma unroll
            for (int s = 8; s >= 1; s >>= 1)
                m = fmaxf(m, __shfl_xor(m, s, 16));
            const float e = pad ? 0.f : __expf(lg[h] - m);
            float sum = e;
            #pragma unroll
            for (int s = 8; s >= 1; s >>= 1)
                sum += __shfl_xor(sum, s, 16);
            // pad coef 0 == ref (exp(-1e9-m)==0); all-pad row -> y=0 -> relu(bbar)
            c[h] = pad ? 0.f : e / sum;
        }
        *(float4*)&coefs_s[k][node][0] = make_float4(c[0], c[1], c[2], c[3]);
        sidx_s[node][k] = safe;
    }
    __syncthreads();

    const int wid  = tid >> 6;
    const int lane = tid & 63;

    // ---- P2: row-gather; wave owns nodes [wid*4, wid*4+4), contiguous rows ----
    {
        const int hw = lane >> 5;         // half-wave selects node parity
        const int sl = lane & 31;         // 16B slot within the 512B row
        const _Float16* xsl = xh + sl * 8;

        float y[2][H_N][8];               // node = wid*4 + 2*i + hw
        #pragma unroll
        for (int i = 0; i < 2; ++i)
            #pragma unroll
            for (int h = 0; h < H_N; ++h)
                #pragma unroll
                for (int j = 0; j < 8; ++j) y[i][h][j] = 0.f;

        #pragma unroll 4
        for (int k = 0; k < K_N; ++k) {
            #pragma unroll
            for (int i = 0; i < 2; ++i) {
                const int n  = wid * 4 + 2 * i + hw;
                const int si = sidx_s[n][k];
                const f16x8 xv = *(const f16x8*)&xsl[(size_t)si * D_N];
                const float4 c = *(const float4*)&coefs_s[k][n][0];
                const float ch4[H_N] = { c.x, c.y, c.z, c.w };
                #pragma unroll
                for (int h = 0; h < H_N; ++h)
                    #pragma unroll
                    for (int j = 0; j < 8; ++j)
                        y[i][h][j] = fmaf(ch4[h], (float)xv[j], y[i][h][j]);
            }
        }
        // store fp16 A-fragments, XOR-swizzled (write: contiguous permuted 512B)
        #pragma unroll
        for (int i = 0; i < 2; ++i) {
            const int n    = wid * 4 + 2 * i + hw;
            const int slot = n * 32 + (sl ^ n);
            #pragma unroll
            for (int h = 0; h < H_N; ++h) {
                f16x8 v;
                #pragma unroll
                for (int j = 0; j < 8; ++j) v[j] = (_Float16)y[i][h][j];
                *(f16x8*)&yl[(size_t)(h * 512 + slot) * 8] = v;
            }
        }
    }
    __syncthreads();

    // ---- P3: col tiles wid*2, wid*2+1 over full K (4h x 8 slices) ----
    const int m = lane & 15;              // node / C col
    const int q = lane >> 4;              // k-group / C row group
    f32x4 acc0 = (f32x4){0.f, 0.f, 0.f, 0.f};
    f32x4 acc1 = (f32x4){0.f, 0.f, 0.f, 0.f};
    {
        const _Float16* Wb = Wt + (size_t)lane * 8;
        #pragma unroll
        for (int h = 0; h < H_N; ++h) {
            #pragma unroll
            for (int s = 0; s < 8; ++s) {
                const int slot = m * 32 + ((s * 4 + q) ^ m);
                const f16x8 af = *(const f16x8*)&yl[(size_t)(h * 512 + slot) * 8];
                const size_t fb = (size_t)((h * 8 + s) * 8 + wid * 2) * 512;
                const f16x8 b0 = *(const f16x8*)&Wb[fb];
                const f16x8 b1 = *(const f16x8*)&Wb[fb + 512];
                acc0 = __builtin_amdgcn_mfma_f32_16x16x32_f16(af, b0, acc0, 0, 0, 0);
                acc1 = __builtin_amdgcn_mfma_f32_16x16x32_f16(af, b1, acc1, 0, 0, 0);
            }
        }
    }

    // ---- epilogue: mean heads + mean bias + relu; C: col=m, row=q*4+r ----
    #pragma unroll
    for (int nt = 0; nt < 2; ++nt) {
        const f32x4 acc = nt ? acc1 : acc0;
        const int col = (wid * 2 + nt) * 16 + m;
        const float bb = b[col] + b[O_N + col] + b[2 * O_N + col] + b[3 * O_N + col];
        #pragma unroll
        for (int r = 0; r < 4; ++r) {
            const int node = q * 4 + r;
            out[(size_t)(v0 + node) * O_N + col] = fmaxf(0.25f * (acc[r] + bb), 0.f);
        }
    }
}

extern "C" void kernel_launch(void* const* d_in, const int* in_sizes, int n_in,
                              void* d_out, int out_size, void* d_ws, size_t ws_size,
                              hipStream_t stream) {
    const float* x      = (const float*)d_in[0];
    const float* W      = (const float*)d_in[1];
    const float* a      = (const float*)d_in[2];
    const float* b      = (const float*)d_in[3];
    const int*   adj    = (const int*)d_in[4];
    const int*   mask_p = (const int*)d_in[5];
    float*       out    = (float*)d_out;

    // ws layout (bytes)
    char* p = (char*)d_ws;
    float*    attn4 = (float*)p;                     //    320,000
    _Float16* xh    = (_Float16*)(p + 320000);       // 10,240,000
    _Float16* Wt    = (_Float16*)(p + 10560000);     //    262,144
    float*    wt    = (float*)(p + 10822144);        //      4,096  (~10.8MB)

    prep_kernel<<<68, 256, 0, stream>>>(W, a, Wt, wt);
    xsplit_attn_kernel<<<V_N / 4, 256, 0, stream>>>(x, wt, xh, attn4);
    gat_kernel<<<V_N / TM, 256, 0, stream>>>(xh, attn4, Wt, b, adj, mask_p, out);
}